// Round 10
// baseline (4999.818 us; speedup 1.0000x reference)
//
#include <hip/hip_runtime.h>

#define B_ 16
#define T_ 256
#define E_ 512
#define H_ 1024
#define V_ 32000

typedef float f32x4 __attribute__((ext_vector_type(4)));
typedef short short8 __attribute__((ext_vector_type(8)));

typedef __attribute__((address_space(1))) const void gas_t;
typedef __attribute__((address_space(3))) void las_t;

__device__ __forceinline__ unsigned short f2bf(float x) {
    unsigned int u = __float_as_uint(x);
    u += 0x7FFF + ((u >> 16) & 1);            // RTNE
    return (unsigned short)(u >> 16);
}
__device__ __forceinline__ float bf2f(unsigned short b) {
    return __uint_as_float(((unsigned int)b) << 16);
}
// fast gates: v_exp + fast-div; saturation-safe, ~2e-7 error
__device__ __forceinline__ float fsig(float x) {
    return __fdividef(1.f, 1.f + __expf(-x));
}
__device__ __forceinline__ float ftanh(float x) {
    float xc = fminf(fmaxf(x, -15.f), 15.f);
    float e  = __expf(-2.f * xc);
    return __fdividef(1.f - e, 1.f + e);
}

// ---------------------------------------------------------------------------
// Embedding gather fused with bf16 hi/lo split: emb[tokens] -> Ah/Al [4096,512]
// ---------------------------------------------------------------------------
__global__ __launch_bounds__(256)
void gather_cvt_k(const int* __restrict__ tokens, const float* __restrict__ emb,
                  unsigned short* __restrict__ Ah, unsigned short* __restrict__ Al)
{
    int i  = blockIdx.x * 256 + threadIdx.x;   // float4 id; 4096*128 total
    int bt = i >> 7;
    int e4 = i & 127;
    float4 v = ((const float4*)(emb + (size_t)tokens[bt] * E_))[e4];
    ushort4 h, l;
    h.x = f2bf(v.x); l.x = f2bf(v.x - bf2f(h.x));
    h.y = f2bf(v.y); l.y = f2bf(v.y - bf2f(h.y));
    h.z = f2bf(v.z); l.z = f2bf(v.z - bf2f(h.z));
    h.w = f2bf(v.w); l.w = f2bf(v.w - bf2f(h.w));
    ((ushort4*)Ah)[i] = h;
    ((ushort4*)Al)[i] = l;
}

// ---------------------------------------------------------------------------
// fp32 -> bf16 hi/lo split (A activations, row-major, no transpose)
// ---------------------------------------------------------------------------
__global__ __launch_bounds__(256)
void cvt_k(const float* __restrict__ A, unsigned short* __restrict__ Ah,
           unsigned short* __restrict__ Al)
{
    int i = blockIdx.x * 256 + threadIdx.x;    // float4 id
    float4 v = ((const float4*)A)[i];
    ushort4 h, l;
    h.x = f2bf(v.x); l.x = f2bf(v.x - bf2f(h.x));
    h.y = f2bf(v.y); l.y = f2bf(v.y - bf2f(h.y));
    h.z = f2bf(v.z); l.z = f2bf(v.z - bf2f(h.z));
    h.w = f2bf(v.w); l.w = f2bf(v.w - bf2f(h.w));
    ((ushort4*)Ah)[i] = h;
    ((ushort4*)Al)[i] = l;
}

// ---------------------------------------------------------------------------
// Weight transpose + split: W fp32 [K][Nfull], col slice [n0, n0+NS) ->
// Bh/Bl bf16 [NS][K]. 32x32 LDS tiles, +1 pad, coalesced both sides.
// ---------------------------------------------------------------------------
__global__ __launch_bounds__(256)
void twz_k(const float* __restrict__ W, unsigned short* __restrict__ Bh,
           unsigned short* __restrict__ Bl, int Kd, int Nfull, int n0)
{
    __shared__ float tile[32][33];
    int t  = threadIdx.x;
    int tx = t & 31, ty = t >> 5;              // ty 0..7
    int nb = blockIdx.x * 32, kb = blockIdx.y * 32;
    #pragma unroll
    for (int i = 0; i < 4; ++i)
        tile[ty + i * 8][tx] = W[(size_t)(kb + ty + i * 8) * Nfull + n0 + nb + tx];
    __syncthreads();
    #pragma unroll
    for (int i = 0; i < 4; ++i) {
        float v = tile[tx][ty + i * 8];
        unsigned short h = f2bf(v), l = f2bf(v - bf2f(h));
        size_t o = (size_t)(nb + ty + i * 8) * Kd + kb + tx;
        Bh[o] = h; Bl[o] = l;
    }
}

// ---------------------------------------------------------------------------
// Split-bf16 3-pass MFMA GEMM (round-5-verified, unchanged): staging via
// global_load_lds width 16, pre-swizzled source, XOR-swizzled LDS reads.
// ---------------------------------------------------------------------------
template<int DO_MASK>
__global__ __launch_bounds__(256)
void mgemm_k(const unsigned short* __restrict__ Ah, const unsigned short* __restrict__ Al,
             const unsigned short* __restrict__ Bh, const unsigned short* __restrict__ Bl,
             const float* __restrict__ bias, float* __restrict__ C,
             const int* __restrict__ tokens, int K, int ldc, int n0)
{
    __shared__ unsigned short LDSS[4][128 * 64];   // 64 KB: Ah,Al,Bh,Bl planes

    const int tid  = threadIdx.x;
    const int bm   = blockIdx.y * 128;
    const int bn   = blockIdx.x * 128;
    const int w    = tid >> 6, lane = tid & 63;
    const int wm   = (w >> 1) * 64, wn = (w & 1) * 64;
    const int l15  = lane & 15, lhi = lane >> 4;

    const unsigned short* gp = (w == 0) ? Ah : (w == 1) ? Al : (w == 2) ? Bh : Bl;
    const int rb = (w < 2) ? bm : bn;
    const int srow = lane >> 3;
    const int scol = (lane & 7) ^ srow;
    unsigned short* lbase = &LDSS[w][0];

    f32x4 acc[4][4];
    #pragma unroll
    for (int mi = 0; mi < 4; ++mi)
        #pragma unroll
        for (int ni = 0; ni < 4; ++ni) {
            f32x4 z = {0.f, 0.f, 0.f, 0.f};
            acc[mi][ni] = z;
        }

    for (int kt = 0; kt < K; kt += 64) {
        #pragma unroll
        for (int c = 0; c < 16; ++c) {
            const unsigned short* src =
                gp + (size_t)(rb + c * 8 + srow) * K + kt + scol * 8;
            __builtin_amdgcn_global_load_lds((gas_t*)src,
                                             (las_t*)(lbase + c * 512), 16, 0, 0);
        }
        __syncthreads();
        #pragma unroll
        for (int ks = 0; ks < 2; ++ks) {
            short8 ah[4], al[4], bh[4], bl[4];
            const int s = ks * 4 + lhi;
            #pragma unroll
            for (int mi = 0; mi < 4; ++mi) {
                int m = wm + mi * 16 + l15;
                int off = m * 64 + ((s ^ (m & 7)) * 8);
                ah[mi] = *(const short8*)(&LDSS[0][off]);
                al[mi] = *(const short8*)(&LDSS[1][off]);
            }
            #pragma unroll
            for (int ni = 0; ni < 4; ++ni) {
                int n = wn + ni * 16 + l15;
                int off = n * 64 + ((s ^ (n & 7)) * 8);
                bh[ni] = *(const short8*)(&LDSS[2][off]);
                bl[ni] = *(const short8*)(&LDSS[3][off]);
            }
            #pragma unroll
            for (int mi = 0; mi < 4; ++mi)
                #pragma unroll
                for (int ni = 0; ni < 4; ++ni) {
                    acc[mi][ni] = __builtin_amdgcn_mfma_f32_16x16x32_bf16(
                        ah[mi], bh[ni], acc[mi][ni], 0, 0, 0);
                    acc[mi][ni] = __builtin_amdgcn_mfma_f32_16x16x32_bf16(
                        ah[mi], bl[ni], acc[mi][ni], 0, 0, 0);
                    acc[mi][ni] = __builtin_amdgcn_mfma_f32_16x16x32_bf16(
                        al[mi], bh[ni], acc[mi][ni], 0, 0, 0);
                }
        }
        __syncthreads();
    }

    #pragma unroll
    for (int mi = 0; mi < 4; ++mi) {
        #pragma unroll
        for (int r = 0; r < 4; ++r) {
            int row = bm + wm + mi * 16 + lhi * 4 + r;
            bool msk = true;
            if (DO_MASK) msk = (tokens[row] != 0);
            #pragma unroll
            for (int ni = 0; ni < 4; ++ni) {
                int col = bn + wn + ni * 16 + l15;
                float v = acc[mi][ni][r] + bias[n0 + col];
                if (DO_MASK && !msk) v = ((n0 + col) == 0) ? 1.f : 0.f;
                C[(size_t)row * ldc + n0 + col] = v;
            }
        }
    }
}

// ---------------------------------------------------------------------------
// Wh [1024][4096] fp32 -> register-fragment image WhF (bf16 hi/lo B-frags).
// Also resets the 64 packed per-block flag words.
// ---------------------------------------------------------------------------
__global__ __launch_bounds__(256)
void wprep_k(const float* __restrict__ Wh, uint4* __restrict__ WhF,
             unsigned* __restrict__ flags)
{
    int flat = blockIdx.x * 256 + threadIdx.x;      // 0 .. 524287
    if (flat < 64) flags[flat] = 0;
    int l  = flat & 63;
    int kf = (flat >> 6) & 3;
    int ct = (flat >> 8) & 3;
    int w  = (flat >> 10) & 7;
    int bx = flat >> 13;                            // 0..63
    int k0  = w * 128 + kf * 32 + 8 * (l >> 4);
    int col = ct * H_ + bx * 16 + (l & 15);
    unsigned short hi[8], lo[8];
    #pragma unroll
    for (int j = 0; j < 8; ++j) {
        float v = Wh[(size_t)(k0 + j) * (4 * H_) + col];
        hi[j] = f2bf(v); lo[j] = f2bf(v - bf2f(hi[j]));
    }
    size_t base = ((((size_t)bx * 8 + w) * 4 + ct) * 4 + kf) * 2;
    WhF[(base + 0) * 64 + l] = *(uint4*)hi;
    WhF[(base + 1) * 64 + l] = *(uint4*)lo;
}

// ---------------------------------------------------------------------------
// Persistent MFMA LSTM layer. 64 blocks x 512 threads (cooperative).
// Round-10 changes (critical-path trimming; exchange mechanism unchanged):
//  (1) counted vmcnt: xz loads (issued last, plain-cached) stay OUTSTANDING
//      through the MFMA phase (vmcnt(4) waits h-loads only); drained at
//      gate start with vmcnt(0).
//  (2) per-gate-wave BYTE flags: flag word per block = 4 bytes, gate wave w
//      stores its byte after draining ITS OWN hT stores (drains parallel,
//      one syncthreads removed, no w0 relay).
//  (3) per-wave producer-group poll: wave w consumes k in [w*128,(w+1)*128)
//      = producers w*8..w*8+7 only; lane l polls flags[w*8+(l&7)] for
//      == t*0x01010101 at step top. Lead bound <= 1 step => '==' is safe.
//  (4) tokens preloaded to LDS (16 KB); hseq store moved AFTER flag store
//      (only consumed after kernel end).
// ---------------------------------------------------------------------------
__global__ __launch_bounds__(512, 2)
void lstm_pers_k(const float* __restrict__ xz,   // [B*T][4H]
                 const uint4* __restrict__ WhF,
                 float* __restrict__ hseq,       // [B*T][H]
                 unsigned* __restrict__ hT,      // [2][H][16] packed bf16 pair
                 const int* __restrict__ tokens,
                 unsigned* __restrict__ flags)   // [64] packed 4-byte flags
{
    __shared__ float Rs2[4 * 2048];               // 32 KB: r-plane scalar layout
    __shared__ int   tokLDS[B_ * T_];             // 16 KB

    const int tid = threadIdx.x;
    const int bx  = blockIdx.x;                   // 0..63
    const int w   = tid >> 6;
    const int l   = tid & 63;
    const int l15 = l & 15, lhi = l >> 4;
    const int u   = bx * 16 + l15;

    // one-time: tokens -> LDS (coalesced)
    #pragma unroll
    for (int i = tid; i < B_ * T_; i += 512) tokLDS[i] = tokens[i];

    // one-time load of register-resident Wh fragments (coalesced)
    short8 Bhi[4][4], Blo[4][4];
    {
        const uint4* p = WhF + (((size_t)bx * 8 + w) * 32) * 64;
        #pragma unroll
        for (int ct = 0; ct < 4; ++ct)
            #pragma unroll
            for (int kf = 0; kf < 4; ++kf) {
                uint4 hv = p[((ct * 4 + kf) * 2 + 0) * 64 + l];
                uint4 lv = p[((ct * 4 + kf) * 2 + 1) * 64 + l];
                Bhi[ct][kf] = *(short8*)&hv;
                Blo[ct][kf] = *(short8*)&lv;
            }
    }
    __syncthreads();                              // tokLDS ready

    float c1 = 0.f, h1 = 0.f;                     // gate-wave cell state
    const int   bgate   = lhi * 4 + w;            // gate-wave batch (w<4)
    const size_t bt_base = (size_t)bgate * T_;

    for (int t = 0; t < T_; ++t) {
        // (3) per-wave producer-group poll: h(t-1) ready from my 8 producers
        if (t > 0) {
            const unsigned pat = (unsigned)t * 0x01010101u;
            const int pidx = w * 8 + (l & 7);
            while (true) {
                unsigned fv = __hip_atomic_load(&flags[pidx],
                    __ATOMIC_RELAXED, __HIP_MEMORY_SCOPE_AGENT);
                if (__all(fv == pat)) break;
                __builtin_amdgcn_s_sleep(1);
            }
        }

        // issue h loads (32, MALL-coherent), then xz loads (4, plain-cached)
        unsigned hd[4][8];
        if (t > 0) {
            const unsigned* hTp = hT + (size_t)((t - 1) & 1) * (H_ * 16);
            #pragma unroll
            for (int kf = 0; kf < 4; ++kf) {
                const int k0 = w * 128 + kf * 32 + 8 * lhi;
                #pragma unroll
                for (int j = 0; j < 8; ++j) {
                    const unsigned* ap = hTp + (k0 + j) * 16 + l15;
                    asm volatile("global_load_dword %0, %1, off sc0 sc1"
                                 : "=&v"(hd[kf][j]) : "v"(ap));
                }
            }
        }
        float xzr[4];
        if (w < 4) {
            size_t bt = bt_base + t;
            #pragma unroll
            for (int ct = 0; ct < 4; ++ct) {
                const float* ap = xz + bt * 4096 + (size_t)ct * H_ + u;
                asm volatile("global_load_dword %0, %1, off"
                             : "=&v"(xzr[ct]) : "v"(ap));
            }
        }

        if (t > 0) {
            // (1) wait h only; xz stays outstanding through MFMA (gate waves)
            if (w < 4) asm volatile("s_waitcnt vmcnt(4)" ::: "memory");
            else       asm volatile("s_waitcnt vmcnt(0)" ::: "memory");
            __builtin_amdgcn_sched_barrier(0);

            f32x4 acc0 = {0.f,0.f,0.f,0.f}, acc1 = acc0, acc2 = acc0, acc3 = acc0;
            #pragma unroll
            for (int kf = 0; kf < 4; ++kf) {
                unsigned short hh[8], hl[8];
                #pragma unroll
                for (int j = 0; j < 8; ++j) {
                    unsigned d = hd[kf][j];
                    hh[j] = (unsigned short)(d >> 16);
                    hl[j] = (unsigned short)(d & 0xFFFFu);
                }
                short8 ah = *(short8*)hh, al = *(short8*)hl;
                acc0 = __builtin_amdgcn_mfma_f32_16x16x32_bf16(ah, Bhi[0][kf], acc0, 0,0,0);
                acc0 = __builtin_amdgcn_mfma_f32_16x16x32_bf16(ah, Blo[0][kf], acc0, 0,0,0);
                acc0 = __builtin_amdgcn_mfma_f32_16x16x32_bf16(al, Bhi[0][kf], acc0, 0,0,0);
                acc1 = __builtin_amdgcn_mfma_f32_16x16x32_bf16(ah, Bhi[1][kf], acc1, 0,0,0);
                acc1 = __builtin_amdgcn_mfma_f32_16x16x32_bf16(ah, Blo[1][kf], acc1, 0,0,0);
                acc1 = __builtin_amdgcn_mfma_f32_16x16x32_bf16(al, Bhi[1][kf], acc1, 0,0,0);
                acc2 = __builtin_amdgcn_mfma_f32_16x16x32_bf16(ah, Bhi[2][kf], acc2, 0,0,0);
                acc2 = __builtin_amdgcn_mfma_f32_16x16x32_bf16(ah, Blo[2][kf], acc2, 0,0,0);
                acc2 = __builtin_amdgcn_mfma_f32_16x16x32_bf16(al, Bhi[2][kf], acc2, 0,0,0);
                acc3 = __builtin_amdgcn_mfma_f32_16x16x32_bf16(ah, Bhi[3][kf], acc3, 0,0,0);
                acc3 = __builtin_amdgcn_mfma_f32_16x16x32_bf16(ah, Blo[3][kf], acc3, 0,0,0);
                acc3 = __builtin_amdgcn_mfma_f32_16x16x32_bf16(al, Bhi[3][kf], acc3, 0,0,0);
            }
            #pragma unroll
            for (int r = 0; r < 4; ++r) {
                Rs2[r * 2048 + (0 * 8 + w) * 64 + l] = acc0[r];
                Rs2[r * 2048 + (1 * 8 + w) * 64 + l] = acc1[r];
                Rs2[r * 2048 + (2 * 8 + w) * 64 + l] = acc2[r];
                Rs2[r * 2048 + (3 * 8 + w) * 64 + l] = acc3[r];
            }
        }
        __syncthreads();                          // Rs2 ready

        // gate phase: waves 0-3 in parallel (wave w = batch-group r=w)
        if (w < 4) {
            asm volatile("s_waitcnt vmcnt(0)" ::: "memory");  // xz arrived
            __builtin_amdgcn_sched_barrier(0);
            float z[4];
            #pragma unroll
            for (int ct = 0; ct < 4; ++ct) {
                float s = 0.f;
                if (t > 0) {
                    #pragma unroll
                    for (int w2 = 0; w2 < 8; ++w2)
                        s += Rs2[w * 2048 + (ct * 8 + w2) * 64 + l];
                }
                z[ct] = s + xzr[ct];
            }
            float i_ = fsig(z[0]);
            float f_ = fsig(z[1]);
            float g_ = ftanh(z[2]);
            float o_ = fsig(z[3]);
            float c_new = f_ * c1 + i_ * g_;
            float h_new = o_ * ftanh(c_new);
            bool  m  = (tokLDS[bt_base + t] != 0);
            float h2 = m ? h_new : h1;
            c1 = m ? c_new : c1;
            h1 = h2;
            if (t + 1 < T_) {
                unsigned short hh = f2bf(h2);
                unsigned short hl = f2bf(h2 - bf2f(hh));
                unsigned pack = ((unsigned)hh << 16) | hl;
                __hip_atomic_store(&hT[(size_t)(t & 1) * (H_ * 16) + u * 16 + bgate],
                                   pack, __ATOMIC_RELAXED, __HIP_MEMORY_SCOPE_AGENT);
                asm volatile("s_waitcnt vmcnt(0)" ::: "memory");  // own hT drained
                // (2) per-wave byte flag: flags[bx] byte w = t+1
                if (l15 == 0 && lhi == 0) {
                    const unsigned char* fb =
                        (const unsigned char*)flags + (bx * 4 + w);
                    unsigned val = (unsigned)(t + 1);
                    asm volatile("global_store_byte %0, %1, off sc0 sc1"
                                 :: "v"(fb), "v"(val) : "memory");
                }
            }
            hseq[(bt_base + t) * H_ + u] = h2;    // off critical path
        }
        __syncthreads();                          // Rs2 reusable next step
    }
}

// ---------------------------------------------------------------------------
extern "C" void kernel_launch(void* const* d_in, const int* in_sizes, int n_in,
                              void* d_out, int out_size, void* d_ws, size_t ws_size,
                              hipStream_t stream)
{
    const int*   tokens = (const int*)d_in[0];
    const float* emb    = (const float*)d_in[1];
    const float* Wx0    = (const float*)d_in[2];
    const float* Wh0    = (const float*)d_in[3];
    const float* b0     = (const float*)d_in[4];
    const float* Wx1    = (const float*)d_in[5];
    const float* Wh1    = (const float*)d_in[6];
    const float* b1     = (const float*)d_in[7];
    const float* Wout   = (const float*)d_in[8];
    const float* bout   = (const float*)d_in[9];
    float* out = (float*)d_out;

    // d_ws: bf16 planes (~82.3 MB) + hT double buffer (128 KB) + flags
    unsigned short* wsu = (unsigned short*)d_ws;
    const size_t BPL = (size_t)16000 * 1024;          // B-plane slot (shorts)
    const size_t AP  = (size_t)4096 * 1024;           // A-plane slot (shorts)
    unsigned short* Bh  = wsu;
    unsigned short* Bl  = wsu + BPL;
    unsigned short* Ahp = wsu + 2 * BPL;
    unsigned short* Alp = Ahp + AP;
    unsigned* hT    = (unsigned*)(wsu + 2 * BPL + 2 * AP);   // 2*16384 u32
    unsigned* flags = hT + 2 * (size_t)H_ * 16;              // 64 words

    // d_out head used as fp32 scratch; all dead before final GEMM writes logits.
    float* f   = (float*)d_out;
    float* xz  = f;                                   // 16.78M floats
    float* WhF = xz + (size_t)4096 * 4096;            // 4.19M (frag image)
    float* h0  = WhF + (size_t)1024 * 4096;           // 4.19M
    float* h1  = h0 + (size_t)4096 * 1024;            // 4.19M

    dim3 blk(256);

    // ---- layer 0 input projection ----
    gather_cvt_k<<<2048, blk, 0, stream>>>(tokens, emb, Ahp, Alp);
    twz_k<<<dim3(128, 16), blk, 0, stream>>>(Wx0, Bh, Bl, 512, 4096, 0);
    mgemm_k<0><<<dim3(32, 32), blk, 0, stream>>>(Ahp, Alp, Bh, Bl, b0, xz,
                                                 nullptr, 512, 4096, 0);
    // ---- layer 0 recurrence (persistent) ----
    wprep_k<<<2048, blk, 0, stream>>>(Wh0, (uint4*)WhF, flags);
    {
        void* args[] = {(void*)&xz, (void*)&WhF, (void*)&h0, (void*)&hT,
                        (void*)&tokens, (void*)&flags};
        hipLaunchCooperativeKernel((void*)lstm_pers_k, dim3(64), dim3(512),
                                   args, 0, stream);
    }
    // ---- layer 1 input projection ----
    cvt_k<<<4096, blk, 0, stream>>>(h0, Ahp, Alp);
    twz_k<<<dim3(128, 32), blk, 0, stream>>>(Wx1, Bh, Bl, 1024, 4096, 0);
    mgemm_k<0><<<dim3(32, 32), blk, 0, stream>>>(Ahp, Alp, Bh, Bl, b1, xz,
                                                 nullptr, 1024, 4096, 0);
    // ---- layer 1 recurrence (persistent) ----
    wprep_k<<<2048, blk, 0, stream>>>(Wh1, (uint4*)WhF, flags);
    {
        void* args[] = {(void*)&xz, (void*)&WhF, (void*)&h1, (void*)&hT,
                        (void*)&tokens, (void*)&flags};
        hipLaunchCooperativeKernel((void*)lstm_pers_k, dim3(64), dim3(512),
                                   args, 0, stream);
    }
    // ---- vocab projection in two N-halves (bounds ws usage) ----
    cvt_k<<<4096, blk, 0, stream>>>(h1, Ahp, Alp);
    twz_k<<<dim3(500, 32), blk, 0, stream>>>(Wout, Bh, Bl, 1024, 32000, 0);
    mgemm_k<1><<<dim3(125, 32), blk, 0, stream>>>(Ahp, Alp, Bh, Bl, bout, out,
                                                  tokens, 1024, 32000, 0);
    twz_k<<<dim3(500, 32), blk, 0, stream>>>(Wout, Bh, Bl, 1024, 32000, 16000);
    mgemm_k<1><<<dim3(125, 32), blk, 0, stream>>>(Ahp, Alp, Bh, Bl, bout, out,
                                                  tokens, 1024, 32000, 16000);
}

// Round 11
// 3886.316 us; speedup vs baseline: 1.2865x; 1.2865x over previous
//
#include <hip/hip_runtime.h>

#define B_ 16
#define T_ 256
#define E_ 512
#define H_ 1024
#define V_ 32000

typedef float f32x4 __attribute__((ext_vector_type(4)));
typedef short short8 __attribute__((ext_vector_type(8)));

typedef __attribute__((address_space(1))) const void gas_t;
typedef __attribute__((address_space(3))) void las_t;

__device__ __forceinline__ unsigned short f2bf(float x) {
    unsigned int u = __float_as_uint(x);
    u += 0x7FFF + ((u >> 16) & 1);            // RTNE
    return (unsigned short)(u >> 16);
}
__device__ __forceinline__ float bf2f(unsigned short b) {
    return __uint_as_float(((unsigned int)b) << 16);
}
// fast gates: v_exp + fast-div; saturation-safe, ~2e-7 error
__device__ __forceinline__ float fsig(float x) {
    return __fdividef(1.f, 1.f + __expf(-x));
}
__device__ __forceinline__ float ftanh(float x) {
    float xc = fminf(fmaxf(x, -15.f), 15.f);
    float e  = __expf(-2.f * xc);
    return __fdividef(1.f - e, 1.f + e);
}

// ---------------------------------------------------------------------------
// Embedding gather fused with bf16 hi/lo split: emb[tokens] -> Ah/Al [4096,512]
// ---------------------------------------------------------------------------
__global__ __launch_bounds__(256)
void gather_cvt_k(const int* __restrict__ tokens, const float* __restrict__ emb,
                  unsigned short* __restrict__ Ah, unsigned short* __restrict__ Al)
{
    int i  = blockIdx.x * 256 + threadIdx.x;   // float4 id; 4096*128 total
    int bt = i >> 7;
    int e4 = i & 127;
    float4 v = ((const float4*)(emb + (size_t)tokens[bt] * E_))[e4];
    ushort4 h, l;
    h.x = f2bf(v.x); l.x = f2bf(v.x - bf2f(h.x));
    h.y = f2bf(v.y); l.y = f2bf(v.y - bf2f(h.y));
    h.z = f2bf(v.z); l.z = f2bf(v.z - bf2f(h.z));
    h.w = f2bf(v.w); l.w = f2bf(v.w - bf2f(h.w));
    ((ushort4*)Ah)[i] = h;
    ((ushort4*)Al)[i] = l;
}

// ---------------------------------------------------------------------------
// fp32 -> bf16 hi/lo split (A activations, row-major, no transpose)
// ---------------------------------------------------------------------------
__global__ __launch_bounds__(256)
void cvt_k(const float* __restrict__ A, unsigned short* __restrict__ Ah,
           unsigned short* __restrict__ Al)
{
    int i = blockIdx.x * 256 + threadIdx.x;    // float4 id
    float4 v = ((const float4*)A)[i];
    ushort4 h, l;
    h.x = f2bf(v.x); l.x = f2bf(v.x - bf2f(h.x));
    h.y = f2bf(v.y); l.y = f2bf(v.y - bf2f(h.y));
    h.z = f2bf(v.z); l.z = f2bf(v.z - bf2f(h.z));
    h.w = f2bf(v.w); l.w = f2bf(v.w - bf2f(h.w));
    ((ushort4*)Ah)[i] = h;
    ((ushort4*)Al)[i] = l;
}

// ---------------------------------------------------------------------------
// Weight transpose + split: W fp32 [K][Nfull], col slice [n0, n0+NS) ->
// Bh/Bl bf16 [NS][K]. 32x32 LDS tiles, +1 pad, coalesced both sides.
// ---------------------------------------------------------------------------
__global__ __launch_bounds__(256)
void twz_k(const float* __restrict__ W, unsigned short* __restrict__ Bh,
           unsigned short* __restrict__ Bl, int Kd, int Nfull, int n0)
{
    __shared__ float tile[32][33];
    int t  = threadIdx.x;
    int tx = t & 31, ty = t >> 5;              // ty 0..7
    int nb = blockIdx.x * 32, kb = blockIdx.y * 32;
    #pragma unroll
    for (int i = 0; i < 4; ++i)
        tile[ty + i * 8][tx] = W[(size_t)(kb + ty + i * 8) * Nfull + n0 + nb + tx];
    __syncthreads();
    #pragma unroll
    for (int i = 0; i < 4; ++i) {
        float v = tile[tx][ty + i * 8];
        unsigned short h = f2bf(v), l = f2bf(v - bf2f(h));
        size_t o = (size_t)(nb + ty + i * 8) * Kd + kb + tx;
        Bh[o] = h; Bl[o] = l;
    }
}

// ---------------------------------------------------------------------------
// Split-bf16 3-pass MFMA GEMM (round-5-verified core) + round-11 bijective
// XCD swizzle on the block id (nwg % 8 == 0 for all launches here): each
// XCD gets a contiguous chunk of block ids -> consecutive blocks share the
// same A-panel (L2-hot). Pure block-id permutation, correctness-neutral.
// ---------------------------------------------------------------------------
template<int DO_MASK>
__global__ __launch_bounds__(256)
void mgemm_k(const unsigned short* __restrict__ Ah, const unsigned short* __restrict__ Al,
             const unsigned short* __restrict__ Bh, const unsigned short* __restrict__ Bl,
             const float* __restrict__ bias, float* __restrict__ C,
             const int* __restrict__ tokens, int K, int ldc, int n0)
{
    __shared__ unsigned short LDSS[4][128 * 64];   // 64 KB: Ah,Al,Bh,Bl planes

    const int tid  = threadIdx.x;
    // bijective XCD swizzle: lin = 8q+r -> r*(nwg/8)+q
    const int nwg = gridDim.x * gridDim.y;
    int lin = blockIdx.y * gridDim.x + blockIdx.x;
    lin = (lin & 7) * (nwg >> 3) + (lin >> 3);
    const int bm   = (lin / gridDim.x) * 128;
    const int bn   = (lin % gridDim.x) * 128;
    const int w    = tid >> 6, lane = tid & 63;
    const int wm   = (w >> 1) * 64, wn = (w & 1) * 64;
    const int l15  = lane & 15, lhi = lane >> 4;

    const unsigned short* gp = (w == 0) ? Ah : (w == 1) ? Al : (w == 2) ? Bh : Bl;
    const int rb = (w < 2) ? bm : bn;
    const int srow = lane >> 3;
    const int scol = (lane & 7) ^ srow;
    unsigned short* lbase = &LDSS[w][0];

    f32x4 acc[4][4];
    #pragma unroll
    for (int mi = 0; mi < 4; ++mi)
        #pragma unroll
        for (int ni = 0; ni < 4; ++ni) {
            f32x4 z = {0.f, 0.f, 0.f, 0.f};
            acc[mi][ni] = z;
        }

    for (int kt = 0; kt < K; kt += 64) {
        #pragma unroll
        for (int c = 0; c < 16; ++c) {
            const unsigned short* src =
                gp + (size_t)(rb + c * 8 + srow) * K + kt + scol * 8;
            __builtin_amdgcn_global_load_lds((gas_t*)src,
                                             (las_t*)(lbase + c * 512), 16, 0, 0);
        }
        __syncthreads();
        #pragma unroll
        for (int ks = 0; ks < 2; ++ks) {
            short8 ah[4], al[4], bh[4], bl[4];
            const int s = ks * 4 + lhi;
            #pragma unroll
            for (int mi = 0; mi < 4; ++mi) {
                int m = wm + mi * 16 + l15;
                int off = m * 64 + ((s ^ (m & 7)) * 8);
                ah[mi] = *(const short8*)(&LDSS[0][off]);
                al[mi] = *(const short8*)(&LDSS[1][off]);
            }
            #pragma unroll
            for (int ni = 0; ni < 4; ++ni) {
                int n = wn + ni * 16 + l15;
                int off = n * 64 + ((s ^ (n & 7)) * 8);
                bh[ni] = *(const short8*)(&LDSS[2][off]);
                bl[ni] = *(const short8*)(&LDSS[3][off]);
            }
            #pragma unroll
            for (int mi = 0; mi < 4; ++mi)
                #pragma unroll
                for (int ni = 0; ni < 4; ++ni) {
                    acc[mi][ni] = __builtin_amdgcn_mfma_f32_16x16x32_bf16(
                        ah[mi], bh[ni], acc[mi][ni], 0, 0, 0);
                    acc[mi][ni] = __builtin_amdgcn_mfma_f32_16x16x32_bf16(
                        ah[mi], bl[ni], acc[mi][ni], 0, 0, 0);
                    acc[mi][ni] = __builtin_amdgcn_mfma_f32_16x16x32_bf16(
                        al[mi], bh[ni], acc[mi][ni], 0, 0, 0);
                }
        }
        __syncthreads();
    }

    #pragma unroll
    for (int mi = 0; mi < 4; ++mi) {
        #pragma unroll
        for (int r = 0; r < 4; ++r) {
            int row = bm + wm + mi * 16 + lhi * 4 + r;
            bool msk = true;
            if (DO_MASK) msk = (tokens[row] != 0);
            #pragma unroll
            for (int ni = 0; ni < 4; ++ni) {
                int col = bn + wn + ni * 16 + l15;
                float v = acc[mi][ni][r] + bias[n0 + col];
                if (DO_MASK && !msk) v = ((n0 + col) == 0) ? 1.f : 0.f;
                C[(size_t)row * ldc + n0 + col] = v;
            }
        }
    }
}

// ---------------------------------------------------------------------------
// Wh [1024][4096] fp32 -> register-fragment image WhF (bf16 hi/lo B-frags).
// Also resets the 64 packed per-block barrier flags.
// ---------------------------------------------------------------------------
__global__ __launch_bounds__(256)
void wprep_k(const float* __restrict__ Wh, uint4* __restrict__ WhF,
             unsigned* __restrict__ flags)
{
    int flat = blockIdx.x * 256 + threadIdx.x;      // 0 .. 524287
    if (flat < 64) flags[flat] = 0;
    int l  = flat & 63;
    int kf = (flat >> 6) & 3;
    int ct = (flat >> 8) & 3;
    int w  = (flat >> 10) & 7;
    int bx = flat >> 13;                            // 0..63
    int k0  = w * 128 + kf * 32 + 8 * (l >> 4);
    int col = ct * H_ + bx * 16 + (l & 15);
    unsigned short hi[8], lo[8];
    #pragma unroll
    for (int j = 0; j < 8; ++j) {
        float v = Wh[(size_t)(k0 + j) * (4 * H_) + col];
        hi[j] = f2bf(v); lo[j] = f2bf(v - bf2f(hi[j]));
    }
    size_t base = ((((size_t)bx * 8 + w) * 4 + ct) * 4 + kf) * 2;
    WhF[(base + 0) * 64 + l] = *(uint4*)hi;
    WhF[(base + 1) * 64 + l] = *(uint4*)lo;
}

// ---------------------------------------------------------------------------
// Persistent MFMA LSTM layer — EXACT round-9 structure (proven 1430 us/layer):
// pipelined raw sc0/sc1 h-loads (packed bf16 pairs), 4-wave gate split with
// scalar r-plane LDS reduce, fast gates, single-wave-0 word-flag barrier.
// Round-11 delta (only): hseq store moved AFTER the hT drain, so the
// vmcnt(0) before the flag no longer waits for the hseq HBM ack.
// ---------------------------------------------------------------------------
__global__ __launch_bounds__(512, 2)
void lstm_pers_k(const float* __restrict__ xz,   // [B*T][4H]
                 const uint4* __restrict__ WhF,
                 float* __restrict__ hseq,       // [B*T][H]
                 unsigned* __restrict__ hT,      // [2][H][16] packed bf16 pair
                 const int* __restrict__ tokens,
                 unsigned* __restrict__ flags)
{
    __shared__ float Rs2[4 * 2048];               // 32 KB: r-plane scalar layout

    const int tid = threadIdx.x;
    const int bx  = blockIdx.x;                   // 0..63
    const int w   = tid >> 6;
    const int l   = tid & 63;
    const int l15 = l & 15, lhi = l >> 4;
    const int u   = bx * 16 + l15;

    // one-time load of register-resident Wh fragments (coalesced)
    short8 Bhi[4][4], Blo[4][4];
    {
        const uint4* p = WhF + (((size_t)bx * 8 + w) * 32) * 64;
        #pragma unroll
        for (int ct = 0; ct < 4; ++ct)
            #pragma unroll
            for (int kf = 0; kf < 4; ++kf) {
                uint4 hv = p[((ct * 4 + kf) * 2 + 0) * 64 + l];
                uint4 lv = p[((ct * 4 + kf) * 2 + 1) * 64 + l];
                Bhi[ct][kf] = *(short8*)&hv;
                Blo[ct][kf] = *(short8*)&lv;
            }
    }

    float c1 = 0.f, h1 = 0.f;                     // gate-wave cell state
    const size_t bt_base = (size_t)(lhi * 4 + w) * T_;  // gate-wave batch row

    for (int t = 0; t < T_; ++t) {
        // prefetch xz + token for this step (gate waves only; compiler sinks
        // the waitcnt to the gate phase -> overlaps h-load + MFMA)
        float xzr[4];
        int tok = 0;
        if (w < 4) {
            size_t bt = bt_base + t;
            #pragma unroll
            for (int ct = 0; ct < 4; ++ct)
                xzr[ct] = xz[bt * 4096 + (size_t)ct * H_ + u];
            tok = tokens[bt];
        }

        if (t > 0) {
            // pipelined MALL-coherent h loads (packed bf16 pairs)
            const unsigned* hTp = hT + (size_t)((t - 1) & 1) * (H_ * 16);
            unsigned hd[4][8];
            #pragma unroll
            for (int kf = 0; kf < 4; ++kf) {
                const int k0 = w * 128 + kf * 32 + 8 * lhi;
                #pragma unroll
                for (int j = 0; j < 8; ++j) {
                    const unsigned* ap = hTp + (k0 + j) * 16 + l15;
                    asm volatile("global_load_dword %0, %1, off sc0 sc1"
                                 : "=&v"(hd[kf][j]) : "v"(ap));
                }
            }
            asm volatile("s_waitcnt vmcnt(0)" ::: "memory");
            __builtin_amdgcn_sched_barrier(0);

            f32x4 acc0 = {0.f,0.f,0.f,0.f}, acc1 = acc0, acc2 = acc0, acc3 = acc0;
            #pragma unroll
            for (int kf = 0; kf < 4; ++kf) {
                unsigned short hh[8], hl[8];
                #pragma unroll
                for (int j = 0; j < 8; ++j) {
                    unsigned d = hd[kf][j];
                    hh[j] = (unsigned short)(d >> 16);
                    hl[j] = (unsigned short)(d & 0xFFFFu);
                }
                short8 ah = *(short8*)hh, al = *(short8*)hl;
                acc0 = __builtin_amdgcn_mfma_f32_16x16x32_bf16(ah, Bhi[0][kf], acc0, 0,0,0);
                acc0 = __builtin_amdgcn_mfma_f32_16x16x32_bf16(ah, Blo[0][kf], acc0, 0,0,0);
                acc0 = __builtin_amdgcn_mfma_f32_16x16x32_bf16(al, Bhi[0][kf], acc0, 0,0,0);
                acc1 = __builtin_amdgcn_mfma_f32_16x16x32_bf16(ah, Bhi[1][kf], acc1, 0,0,0);
                acc1 = __builtin_amdgcn_mfma_f32_16x16x32_bf16(ah, Blo[1][kf], acc1, 0,0,0);
                acc1 = __builtin_amdgcn_mfma_f32_16x16x32_bf16(al, Bhi[1][kf], acc1, 0,0,0);
                acc2 = __builtin_amdgcn_mfma_f32_16x16x32_bf16(ah, Bhi[2][kf], acc2, 0,0,0);
                acc2 = __builtin_amdgcn_mfma_f32_16x16x32_bf16(ah, Blo[2][kf], acc2, 0,0,0);
                acc2 = __builtin_amdgcn_mfma_f32_16x16x32_bf16(al, Bhi[2][kf], acc2, 0,0,0);
                acc3 = __builtin_amdgcn_mfma_f32_16x16x32_bf16(ah, Bhi[3][kf], acc3, 0,0,0);
                acc3 = __builtin_amdgcn_mfma_f32_16x16x32_bf16(ah, Blo[3][kf], acc3, 0,0,0);
                acc3 = __builtin_amdgcn_mfma_f32_16x16x32_bf16(al, Bhi[3][kf], acc3, 0,0,0);
            }
            // scatter to scalar r-planes (conflict-free b32 stores)
            #pragma unroll
            for (int r = 0; r < 4; ++r) {
                Rs2[r * 2048 + (0 * 8 + w) * 64 + l] = acc0[r];
                Rs2[r * 2048 + (1 * 8 + w) * 64 + l] = acc1[r];
                Rs2[r * 2048 + (2 * 8 + w) * 64 + l] = acc2[r];
                Rs2[r * 2048 + (3 * 8 + w) * 64 + l] = acc3[r];
            }
        }
        __syncthreads();

        // gate phase: waves 0-3 in parallel, wave w = batch-group r=w
        if (w < 4) {
            float z[4];
            #pragma unroll
            for (int ct = 0; ct < 4; ++ct) {
                float s = 0.f;
                if (t > 0) {
                    #pragma unroll
                    for (int w2 = 0; w2 < 8; ++w2)
                        s += Rs2[w * 2048 + (ct * 8 + w2) * 64 + l];
                }
                z[ct] = s + xzr[ct];
            }
            float i_ = fsig(z[0]);
            float f_ = fsig(z[1]);
            float g_ = ftanh(z[2]);
            float o_ = fsig(z[3]);
            float c_new = f_ * c1 + i_ * g_;
            float h_new = o_ * ftanh(c_new);
            bool  m  = (tok != 0);
            float h2 = m ? h_new : h1;
            c1 = m ? c_new : c1;
            h1 = h2;
            size_t bt = bt_base + t;
            if (t + 1 < T_) {
                unsigned short hh = f2bf(h2);
                unsigned short hl = f2bf(h2 - bf2f(hh));
                unsigned pack = ((unsigned)hh << 16) | hl;
                __hip_atomic_store(&hT[(size_t)(t & 1) * (H_ * 16) + u * 16 +
                                       (lhi * 4 + w)], pack,
                                   __ATOMIC_RELAXED, __HIP_MEMORY_SCOPE_AGENT);
                asm volatile("s_waitcnt vmcnt(0)" ::: "memory");  // hT drained
            }
            hseq[bt * H_ + u] = h2;               // off critical path (R11)
        }
        __syncthreads();                          // all gate hT stores drained

        if (w == 0 && t + 1 < T_) {
            if (l == 0)
                __hip_atomic_store(&flags[bx], (unsigned)(t + 1),
                                   __ATOMIC_RELAXED, __HIP_MEMORY_SCOPE_AGENT);
            const unsigned tgt = (unsigned)(t + 1);
            while (true) {
                unsigned fv = __hip_atomic_load(&flags[l],
                    __ATOMIC_RELAXED, __HIP_MEMORY_SCOPE_AGENT);
                if (__all(fv >= tgt)) break;
                __builtin_amdgcn_s_sleep(1);
            }
        }
        __syncthreads();                          // release for next step
    }
}

// ---------------------------------------------------------------------------
extern "C" void kernel_launch(void* const* d_in, const int* in_sizes, int n_in,
                              void* d_out, int out_size, void* d_ws, size_t ws_size,
                              hipStream_t stream)
{
    const int*   tokens = (const int*)d_in[0];
    const float* emb    = (const float*)d_in[1];
    const float* Wx0    = (const float*)d_in[2];
    const float* Wh0    = (const float*)d_in[3];
    const float* b0     = (const float*)d_in[4];
    const float* Wx1    = (const float*)d_in[5];
    const float* Wh1    = (const float*)d_in[6];
    const float* b1     = (const float*)d_in[7];
    const float* Wout   = (const float*)d_in[8];
    const float* bout   = (const float*)d_in[9];
    float* out = (float*)d_out;

    // d_ws: bf16 planes (~82.3 MB) + hT double buffer (128 KB) + flags
    unsigned short* wsu = (unsigned short*)d_ws;
    const size_t BPL = (size_t)16000 * 1024;          // B-plane slot (shorts)
    const size_t AP  = (size_t)4096 * 1024;           // A-plane slot (shorts)
    unsigned short* Bh  = wsu;
    unsigned short* Bl  = wsu + BPL;
    unsigned short* Ahp = wsu + 2 * BPL;
    unsigned short* Alp = Ahp + AP;
    unsigned* hT    = (unsigned*)(wsu + 2 * BPL + 2 * AP);   // 2*16384 u32
    unsigned* flags = hT + 2 * (size_t)H_ * 16;              // 64 words

    // d_out head used as fp32 scratch; all dead before final GEMM writes logits.
    float* f   = (float*)d_out;
    float* xz  = f;                                   // 16.78M floats
    float* WhF = xz + (size_t)4096 * 4096;            // 4.19M (frag image)
    float* h0  = WhF + (size_t)1024 * 4096;           // 4.19M
    float* h1  = h0 + (size_t)4096 * 1024;            // 4.19M

    dim3 blk(256);

    // ---- layer 0 input projection ----
    gather_cvt_k<<<2048, blk, 0, stream>>>(tokens, emb, Ahp, Alp);
    twz_k<<<dim3(128, 16), blk, 0, stream>>>(Wx0, Bh, Bl, 512, 4096, 0);
    mgemm_k<0><<<dim3(32, 32), blk, 0, stream>>>(Ahp, Alp, Bh, Bl, b0, xz,
                                                 nullptr, 512, 4096, 0);
    // ---- layer 0 recurrence (persistent) ----
    wprep_k<<<2048, blk, 0, stream>>>(Wh0, (uint4*)WhF, flags);
    {
        void* args[] = {(void*)&xz, (void*)&WhF, (void*)&h0, (void*)&hT,
                        (void*)&tokens, (void*)&flags};
        hipLaunchCooperativeKernel((void*)lstm_pers_k, dim3(64), dim3(512),
                                   args, 0, stream);
    }
    // ---- layer 1 input projection ----
    cvt_k<<<4096, blk, 0, stream>>>(h0, Ahp, Alp);
    twz_k<<<dim3(128, 32), blk, 0, stream>>>(Wx1, Bh, Bl, 1024, 4096, 0);
    mgemm_k<0><<<dim3(32, 32), blk, 0, stream>>>(Ahp, Alp, Bh, Bl, b1, xz,
                                                 nullptr, 1024, 4096, 0);
    // ---- layer 1 recurrence (persistent) ----
    wprep_k<<<2048, blk, 0, stream>>>(Wh1, (uint4*)WhF, flags);
    {
        void* args[] = {(void*)&xz, (void*)&WhF, (void*)&h1, (void*)&hT,
                        (void*)&tokens, (void*)&flags};
        hipLaunchCooperativeKernel((void*)lstm_pers_k, dim3(64), dim3(512),
                                   args, 0, stream);
    }
    // ---- vocab projection in two N-halves (bounds ws usage) ----
    cvt_k<<<4096, blk, 0, stream>>>(h1, Ahp, Alp);
    twz_k<<<dim3(500, 32), blk, 0, stream>>>(Wout, Bh, Bl, 1024, 32000, 0);
    mgemm_k<1><<<dim3(125, 32), blk, 0, stream>>>(Ahp, Alp, Bh, Bl, bout, out,
                                                  tokens, 1024, 32000, 0);
    twz_k<<<dim3(500, 32), blk, 0, stream>>>(Wout, Bh, Bl, 1024, 32000, 16000);
    mgemm_k<1><<<dim3(125, 32), blk, 0, stream>>>(Ahp, Alp, Bh, Bl, bout, out,
                                                  tokens, 1024, 32000, 16000);
}

// Round 12
// 3882.545 us; speedup vs baseline: 1.2878x; 1.0010x over previous
//
#include <hip/hip_runtime.h>

#define B_ 16
#define T_ 256
#define E_ 512
#define H_ 1024
#define V_ 32000

typedef float f32x4 __attribute__((ext_vector_type(4)));
typedef short short8 __attribute__((ext_vector_type(8)));

typedef __attribute__((address_space(1))) const void gas_t;
typedef __attribute__((address_space(3))) void las_t;

__device__ __forceinline__ unsigned short f2bf(float x) {
    unsigned int u = __float_as_uint(x);
    u += 0x7FFF + ((u >> 16) & 1);            // RTNE
    return (unsigned short)(u >> 16);
}
__device__ __forceinline__ float bf2f(unsigned short b) {
    return __uint_as_float(((unsigned int)b) << 16);
}
// fast gates: v_exp + fast-div; saturation-safe, ~2e-7 error
__device__ __forceinline__ float fsig(float x) {
    return __fdividef(1.f, 1.f + __expf(-x));
}
__device__ __forceinline__ float ftanh(float x) {
    float xc = fminf(fmaxf(x, -15.f), 15.f);
    float e  = __expf(-2.f * xc);
    return __fdividef(1.f - e, 1.f + e);
}

// ---------------------------------------------------------------------------
// Embedding gather fused with bf16 hi/lo split: emb[tokens] -> Ah/Al [4096,512]
// ---------------------------------------------------------------------------
__global__ __launch_bounds__(256)
void gather_cvt_k(const int* __restrict__ tokens, const float* __restrict__ emb,
                  unsigned short* __restrict__ Ah, unsigned short* __restrict__ Al)
{
    int i  = blockIdx.x * 256 + threadIdx.x;   // float4 id; 4096*128 total
    int bt = i >> 7;
    int e4 = i & 127;
    float4 v = ((const float4*)(emb + (size_t)tokens[bt] * E_))[e4];
    ushort4 h, l;
    h.x = f2bf(v.x); l.x = f2bf(v.x - bf2f(h.x));
    h.y = f2bf(v.y); l.y = f2bf(v.y - bf2f(h.y));
    h.z = f2bf(v.z); l.z = f2bf(v.z - bf2f(h.z));
    h.w = f2bf(v.w); l.w = f2bf(v.w - bf2f(h.w));
    ((ushort4*)Ah)[i] = h;
    ((ushort4*)Al)[i] = l;
}

// ---------------------------------------------------------------------------
// fp32 -> bf16 hi/lo split (A activations, row-major, no transpose)
// ---------------------------------------------------------------------------
__global__ __launch_bounds__(256)
void cvt_k(const float* __restrict__ A, unsigned short* __restrict__ Ah,
           unsigned short* __restrict__ Al)
{
    int i = blockIdx.x * 256 + threadIdx.x;    // float4 id
    float4 v = ((const float4*)A)[i];
    ushort4 h, l;
    h.x = f2bf(v.x); l.x = f2bf(v.x - bf2f(h.x));
    h.y = f2bf(v.y); l.y = f2bf(v.y - bf2f(h.y));
    h.z = f2bf(v.z); l.z = f2bf(v.z - bf2f(h.z));
    h.w = f2bf(v.w); l.w = f2bf(v.w - bf2f(h.w));
    ((ushort4*)Ah)[i] = h;
    ((ushort4*)Al)[i] = l;
}

// ---------------------------------------------------------------------------
// Weight transpose + split: W fp32 [K][Nfull], col slice [n0, n0+NS) ->
// Bh/Bl bf16 [NS][K]. 32x32 LDS tiles, +1 pad, coalesced both sides.
// ---------------------------------------------------------------------------
__global__ __launch_bounds__(256)
void twz_k(const float* __restrict__ W, unsigned short* __restrict__ Bh,
           unsigned short* __restrict__ Bl, int Kd, int Nfull, int n0)
{
    __shared__ float tile[32][33];
    int t  = threadIdx.x;
    int tx = t & 31, ty = t >> 5;              // ty 0..7
    int nb = blockIdx.x * 32, kb = blockIdx.y * 32;
    #pragma unroll
    for (int i = 0; i < 4; ++i)
        tile[ty + i * 8][tx] = W[(size_t)(kb + ty + i * 8) * Nfull + n0 + nb + tx];
    __syncthreads();
    #pragma unroll
    for (int i = 0; i < 4; ++i) {
        float v = tile[tx][ty + i * 8];
        unsigned short h = f2bf(v), l = f2bf(v - bf2f(h));
        size_t o = (size_t)(nb + ty + i * 8) * Kd + kb + tx;
        Bh[o] = h; Bl[o] = l;
    }
}

// ---------------------------------------------------------------------------
// Split-bf16 3-pass MFMA GEMM (round-5-verified core) + bijective XCD swizzle.
// ---------------------------------------------------------------------------
template<int DO_MASK>
__global__ __launch_bounds__(256)
void mgemm_k(const unsigned short* __restrict__ Ah, const unsigned short* __restrict__ Al,
             const unsigned short* __restrict__ Bh, const unsigned short* __restrict__ Bl,
             const float* __restrict__ bias, float* __restrict__ C,
             const int* __restrict__ tokens, int K, int ldc, int n0)
{
    __shared__ unsigned short LDSS[4][128 * 64];   // 64 KB: Ah,Al,Bh,Bl planes

    const int tid  = threadIdx.x;
    // bijective XCD swizzle: lin = 8q+r -> r*(nwg/8)+q
    const int nwg = gridDim.x * gridDim.y;
    int lin = blockIdx.y * gridDim.x + blockIdx.x;
    lin = (lin & 7) * (nwg >> 3) + (lin >> 3);
    const int bm   = (lin / gridDim.x) * 128;
    const int bn   = (lin % gridDim.x) * 128;
    const int w    = tid >> 6, lane = tid & 63;
    const int wm   = (w >> 1) * 64, wn = (w & 1) * 64;
    const int l15  = lane & 15, lhi = lane >> 4;

    const unsigned short* gp = (w == 0) ? Ah : (w == 1) ? Al : (w == 2) ? Bh : Bl;
    const int rb = (w < 2) ? bm : bn;
    const int srow = lane >> 3;
    const int scol = (lane & 7) ^ srow;
    unsigned short* lbase = &LDSS[w][0];

    f32x4 acc[4][4];
    #pragma unroll
    for (int mi = 0; mi < 4; ++mi)
        #pragma unroll
        for (int ni = 0; ni < 4; ++ni) {
            f32x4 z = {0.f, 0.f, 0.f, 0.f};
            acc[mi][ni] = z;
        }

    for (int kt = 0; kt < K; kt += 64) {
        #pragma unroll
        for (int c = 0; c < 16; ++c) {
            const unsigned short* src =
                gp + (size_t)(rb + c * 8 + srow) * K + kt + scol * 8;
            __builtin_amdgcn_global_load_lds((gas_t*)src,
                                             (las_t*)(lbase + c * 512), 16, 0, 0);
        }
        __syncthreads();
        #pragma unroll
        for (int ks = 0; ks < 2; ++ks) {
            short8 ah[4], al[4], bh[4], bl[4];
            const int s = ks * 4 + lhi;
            #pragma unroll
            for (int mi = 0; mi < 4; ++mi) {
                int m = wm + mi * 16 + l15;
                int off = m * 64 + ((s ^ (m & 7)) * 8);
                ah[mi] = *(const short8*)(&LDSS[0][off]);
                al[mi] = *(const short8*)(&LDSS[1][off]);
            }
            #pragma unroll
            for (int ni = 0; ni < 4; ++ni) {
                int n = wn + ni * 16 + l15;
                int off = n * 64 + ((s ^ (n & 7)) * 8);
                bh[ni] = *(const short8*)(&LDSS[2][off]);
                bl[ni] = *(const short8*)(&LDSS[3][off]);
            }
            #pragma unroll
            for (int mi = 0; mi < 4; ++mi)
                #pragma unroll
                for (int ni = 0; ni < 4; ++ni) {
                    acc[mi][ni] = __builtin_amdgcn_mfma_f32_16x16x32_bf16(
                        ah[mi], bh[ni], acc[mi][ni], 0, 0, 0);
                    acc[mi][ni] = __builtin_amdgcn_mfma_f32_16x16x32_bf16(
                        ah[mi], bl[ni], acc[mi][ni], 0, 0, 0);
                    acc[mi][ni] = __builtin_amdgcn_mfma_f32_16x16x32_bf16(
                        al[mi], bh[ni], acc[mi][ni], 0, 0, 0);
                }
        }
        __syncthreads();
    }

    #pragma unroll
    for (int mi = 0; mi < 4; ++mi) {
        #pragma unroll
        for (int r = 0; r < 4; ++r) {
            int row = bm + wm + mi * 16 + lhi * 4 + r;
            bool msk = true;
            if (DO_MASK) msk = (tokens[row] != 0);
            #pragma unroll
            for (int ni = 0; ni < 4; ++ni) {
                int col = bn + wn + ni * 16 + l15;
                float v = acc[mi][ni][r] + bias[n0 + col];
                if (DO_MASK && !msk) v = ((n0 + col) == 0) ? 1.f : 0.f;
                C[(size_t)row * ldc + n0 + col] = v;
            }
        }
    }
}

// ---------------------------------------------------------------------------
// Wh [1024][4096] fp32 -> register-fragment image WhF (bf16 hi/lo B-frags).
// Also resets the 64 packed per-block barrier flags.
// ---------------------------------------------------------------------------
__global__ __launch_bounds__(256)
void wprep_k(const float* __restrict__ Wh, uint4* __restrict__ WhF,
             unsigned* __restrict__ flags)
{
    int flat = blockIdx.x * 256 + threadIdx.x;      // 0 .. 524287
    if (flat < 64) flags[flat] = 0;
    int l  = flat & 63;
    int kf = (flat >> 6) & 3;
    int ct = (flat >> 8) & 3;
    int w  = (flat >> 10) & 7;
    int bx = flat >> 13;                            // 0..63
    int k0  = w * 128 + kf * 32 + 8 * (l >> 4);
    int col = ct * H_ + bx * 16 + (l & 15);
    unsigned short hi[8], lo[8];
    #pragma unroll
    for (int j = 0; j < 8; ++j) {
        float v = Wh[(size_t)(k0 + j) * (4 * H_) + col];
        hi[j] = f2bf(v); lo[j] = f2bf(v - bf2f(hi[j]));
    }
    size_t base = ((((size_t)bx * 8 + w) * 4 + ct) * 4 + kf) * 2;
    WhF[(base + 0) * 64 + l] = *(uint4*)hi;
    WhF[(base + 1) * 64 + l] = *(uint4*)lo;
}

// ---------------------------------------------------------------------------
// Persistent MFMA LSTM layer — round-9/11 structure. Round-12 delta (only):
//  (1) __launch_bounds__(512, 1): grid is 64 blocks (grid-limited occupancy),
//      so give the allocator the full 256-VGPR budget.
//  (2) weight fragments PINNED in registers via opaque inline asm after the
//      one-time load: "+v" makes each frag non-rematerializable, so the
//      compiler cannot sink the WhF loads into the t-loop (VGPR_Count=104 in
//      R6-R11 proves the 128 weight VGPRs were NOT arch-register-resident —
//      the per-step 256KB/block L2 reload is the invariant cost that made
//      every barrier experiment null).
// ---------------------------------------------------------------------------
__global__ __launch_bounds__(512, 1)
void lstm_pers_k(const float* __restrict__ xz,   // [B*T][4H]
                 const uint4* __restrict__ WhF,
                 float* __restrict__ hseq,       // [B*T][H]
                 unsigned* __restrict__ hT,      // [2][H][16] packed bf16 pair
                 const int* __restrict__ tokens,
                 unsigned* __restrict__ flags)
{
    __shared__ float Rs2[4 * 2048];               // 32 KB: r-plane scalar layout

    const int tid = threadIdx.x;
    const int bx  = blockIdx.x;                   // 0..63
    const int w   = tid >> 6;
    const int l   = tid & 63;
    const int l15 = l & 15, lhi = l >> 4;
    const int u   = bx * 16 + l15;

    // one-time load of Wh fragments, then PIN in registers (opaque asm)
    short8 Bhi[4][4], Blo[4][4];
    {
        const uint4* p = WhF + (((size_t)bx * 8 + w) * 32) * 64;
        #pragma unroll
        for (int ct = 0; ct < 4; ++ct)
            #pragma unroll
            for (int kf = 0; kf < 4; ++kf) {
                uint4 hv = p[((ct * 4 + kf) * 2 + 0) * 64 + l];
                uint4 lv = p[((ct * 4 + kf) * 2 + 1) * 64 + l];
                Bhi[ct][kf] = *(short8*)&hv;
                Blo[ct][kf] = *(short8*)&lv;
            }
    }
    #pragma unroll
    for (int ct = 0; ct < 4; ++ct)
        #pragma unroll
        for (int kf = 0; kf < 4; ++kf) {
            asm volatile("" : "+v"(Bhi[ct][kf]));
            asm volatile("" : "+v"(Blo[ct][kf]));
        }

    float c1 = 0.f, h1 = 0.f;                     // gate-wave cell state
    const size_t bt_base = (size_t)(lhi * 4 + w) * T_;  // gate-wave batch row

    for (int t = 0; t < T_; ++t) {
        // prefetch xz + token for this step (gate waves only; compiler sinks
        // the waitcnt to the gate phase -> overlaps h-load + MFMA)
        float xzr[4];
        int tok = 0;
        if (w < 4) {
            size_t bt = bt_base + t;
            #pragma unroll
            for (int ct = 0; ct < 4; ++ct)
                xzr[ct] = xz[bt * 4096 + (size_t)ct * H_ + u];
            tok = tokens[bt];
        }

        if (t > 0) {
            // pipelined MALL-coherent h loads (packed bf16 pairs)
            const unsigned* hTp = hT + (size_t)((t - 1) & 1) * (H_ * 16);
            unsigned hd[4][8];
            #pragma unroll
            for (int kf = 0; kf < 4; ++kf) {
                const int k0 = w * 128 + kf * 32 + 8 * lhi;
                #pragma unroll
                for (int j = 0; j < 8; ++j) {
                    const unsigned* ap = hTp + (k0 + j) * 16 + l15;
                    asm volatile("global_load_dword %0, %1, off sc0 sc1"
                                 : "=&v"(hd[kf][j]) : "v"(ap));
                }
            }
            asm volatile("s_waitcnt vmcnt(0)" ::: "memory");
            __builtin_amdgcn_sched_barrier(0);

            f32x4 acc0 = {0.f,0.f,0.f,0.f}, acc1 = acc0, acc2 = acc0, acc3 = acc0;
            #pragma unroll
            for (int kf = 0; kf < 4; ++kf) {
                unsigned short hh[8], hl[8];
                #pragma unroll
                for (int j = 0; j < 8; ++j) {
                    unsigned d = hd[kf][j];
                    hh[j] = (unsigned short)(d >> 16);
                    hl[j] = (unsigned short)(d & 0xFFFFu);
                }
                short8 ah = *(short8*)hh, al = *(short8*)hl;
                acc0 = __builtin_amdgcn_mfma_f32_16x16x32_bf16(ah, Bhi[0][kf], acc0, 0,0,0);
                acc0 = __builtin_amdgcn_mfma_f32_16x16x32_bf16(ah, Blo[0][kf], acc0, 0,0,0);
                acc0 = __builtin_amdgcn_mfma_f32_16x16x32_bf16(al, Bhi[0][kf], acc0, 0,0,0);
                acc1 = __builtin_amdgcn_mfma_f32_16x16x32_bf16(ah, Bhi[1][kf], acc1, 0,0,0);
                acc1 = __builtin_amdgcn_mfma_f32_16x16x32_bf16(ah, Blo[1][kf], acc1, 0,0,0);
                acc1 = __builtin_amdgcn_mfma_f32_16x16x32_bf16(al, Bhi[1][kf], acc1, 0,0,0);
                acc2 = __builtin_amdgcn_mfma_f32_16x16x32_bf16(ah, Bhi[2][kf], acc2, 0,0,0);
                acc2 = __builtin_amdgcn_mfma_f32_16x16x32_bf16(ah, Blo[2][kf], acc2, 0,0,0);
                acc2 = __builtin_amdgcn_mfma_f32_16x16x32_bf16(al, Bhi[2][kf], acc2, 0,0,0);
                acc3 = __builtin_amdgcn_mfma_f32_16x16x32_bf16(ah, Bhi[3][kf], acc3, 0,0,0);
                acc3 = __builtin_amdgcn_mfma_f32_16x16x32_bf16(ah, Blo[3][kf], acc3, 0,0,0);
                acc3 = __builtin_amdgcn_mfma_f32_16x16x32_bf16(al, Bhi[3][kf], acc3, 0,0,0);
            }
            // scatter to scalar r-planes (conflict-free b32 stores)
            #pragma unroll
            for (int r = 0; r < 4; ++r) {
                Rs2[r * 2048 + (0 * 8 + w) * 64 + l] = acc0[r];
                Rs2[r * 2048 + (1 * 8 + w) * 64 + l] = acc1[r];
                Rs2[r * 2048 + (2 * 8 + w) * 64 + l] = acc2[r];
                Rs2[r * 2048 + (3 * 8 + w) * 64 + l] = acc3[r];
            }
        }
        __syncthreads();

        // gate phase: waves 0-3 in parallel, wave w = batch-group r=w
        if (w < 4) {
            float z[4];
            #pragma unroll
            for (int ct = 0; ct < 4; ++ct) {
                float s = 0.f;
                if (t > 0) {
                    #pragma unroll
                    for (int w2 = 0; w2 < 8; ++w2)
                        s += Rs2[w * 2048 + (ct * 8 + w2) * 64 + l];
                }
                z[ct] = s + xzr[ct];
            }
            float i_ = fsig(z[0]);
            float f_ = fsig(z[1]);
            float g_ = ftanh(z[2]);
            float o_ = fsig(z[3]);
            float c_new = f_ * c1 + i_ * g_;
            float h_new = o_ * ftanh(c_new);
            bool  m  = (tok != 0);
            float h2 = m ? h_new : h1;
            c1 = m ? c_new : c1;
            h1 = h2;
            size_t bt = bt_base + t;
            if (t + 1 < T_) {
                unsigned short hh = f2bf(h2);
                unsigned short hl = f2bf(h2 - bf2f(hh));
                unsigned pack = ((unsigned)hh << 16) | hl;
                __hip_atomic_store(&hT[(size_t)(t & 1) * (H_ * 16) + u * 16 +
                                       (lhi * 4 + w)], pack,
                                   __ATOMIC_RELAXED, __HIP_MEMORY_SCOPE_AGENT);
                asm volatile("s_waitcnt vmcnt(0)" ::: "memory");  // hT drained
            }
            hseq[bt * H_ + u] = h2;               // off critical path
        }
        __syncthreads();                          // all gate hT stores drained

        if (w == 0 && t + 1 < T_) {
            if (l == 0)
                __hip_atomic_store(&flags[bx], (unsigned)(t + 1),
                                   __ATOMIC_RELAXED, __HIP_MEMORY_SCOPE_AGENT);
            const unsigned tgt = (unsigned)(t + 1);
            while (true) {
                unsigned fv = __hip_atomic_load(&flags[l],
                    __ATOMIC_RELAXED, __HIP_MEMORY_SCOPE_AGENT);
                if (__all(fv >= tgt)) break;
                __builtin_amdgcn_s_sleep(1);
            }
        }
        __syncthreads();                          // release for next step
    }
}

// ---------------------------------------------------------------------------
extern "C" void kernel_launch(void* const* d_in, const int* in_sizes, int n_in,
                              void* d_out, int out_size, void* d_ws, size_t ws_size,
                              hipStream_t stream)
{
    const int*   tokens = (const int*)d_in[0];
    const float* emb    = (const float*)d_in[1];
    const float* Wx0    = (const float*)d_in[2];
    const float* Wh0    = (const float*)d_in[3];
    const float* b0     = (const float*)d_in[4];
    const float* Wx1    = (const float*)d_in[5];
    const float* Wh1    = (const float*)d_in[6];
    const float* b1     = (const float*)d_in[7];
    const float* Wout   = (const float*)d_in[8];
    const float* bout   = (const float*)d_in[9];
    float* out = (float*)d_out;

    // d_ws: bf16 planes (~82.3 MB) + hT double buffer (128 KB) + flags
    unsigned short* wsu = (unsigned short*)d_ws;
    const size_t BPL = (size_t)16000 * 1024;          // B-plane slot (shorts)
    const size_t AP  = (size_t)4096 * 1024;           // A-plane slot (shorts)
    unsigned short* Bh  = wsu;
    unsigned short* Bl  = wsu + BPL;
    unsigned short* Ahp = wsu + 2 * BPL;
    unsigned short* Alp = Ahp + AP;
    unsigned* hT    = (unsigned*)(wsu + 2 * BPL + 2 * AP);   // 2*16384 u32
    unsigned* flags = hT + 2 * (size_t)H_ * 16;              // 64 words

    // d_out head used as fp32 scratch; all dead before final GEMM writes logits.
    float* f   = (float*)d_out;
    float* xz  = f;                                   // 16.78M floats
    float* WhF = xz + (size_t)4096 * 4096;            // 4.19M (frag image)
    float* h0  = WhF + (size_t)1024 * 4096;           // 4.19M
    float* h1  = h0 + (size_t)4096 * 1024;            // 4.19M

    dim3 blk(256);

    // ---- layer 0 input projection ----
    gather_cvt_k<<<2048, blk, 0, stream>>>(tokens, emb, Ahp, Alp);
    twz_k<<<dim3(128, 16), blk, 0, stream>>>(Wx0, Bh, Bl, 512, 4096, 0);
    mgemm_k<0><<<dim3(32, 32), blk, 0, stream>>>(Ahp, Alp, Bh, Bl, b0, xz,
                                                 nullptr, 512, 4096, 0);
    // ---- layer 0 recurrence (persistent) ----
    wprep_k<<<2048, blk, 0, stream>>>(Wh0, (uint4*)WhF, flags);
    {
        void* args[] = {(void*)&xz, (void*)&WhF, (void*)&h0, (void*)&hT,
                        (void*)&tokens, (void*)&flags};
        hipLaunchCooperativeKernel((void*)lstm_pers_k, dim3(64), dim3(512),
                                   args, 0, stream);
    }
    // ---- layer 1 input projection ----
    cvt_k<<<4096, blk, 0, stream>>>(h0, Ahp, Alp);
    twz_k<<<dim3(128, 32), blk, 0, stream>>>(Wx1, Bh, Bl, 1024, 4096, 0);
    mgemm_k<0><<<dim3(32, 32), blk, 0, stream>>>(Ahp, Alp, Bh, Bl, b1, xz,
                                                 nullptr, 1024, 4096, 0);
    // ---- layer 1 recurrence (persistent) ----
    wprep_k<<<2048, blk, 0, stream>>>(Wh1, (uint4*)WhF, flags);
    {
        void* args[] = {(void*)&xz, (void*)&WhF, (void*)&h1, (void*)&hT,
                        (void*)&tokens, (void*)&flags};
        hipLaunchCooperativeKernel((void*)lstm_pers_k, dim3(64), dim3(512),
                                   args, 0, stream);
    }
    // ---- vocab projection in two N-halves (bounds ws usage) ----
    cvt_k<<<4096, blk, 0, stream>>>(h1, Ahp, Alp);
    twz_k<<<dim3(500, 32), blk, 0, stream>>>(Wout, Bh, Bl, 1024, 32000, 0);
    mgemm_k<1><<<dim3(125, 32), blk, 0, stream>>>(Ahp, Alp, Bh, Bl, bout, out,
                                                  tokens, 1024, 32000, 0);
    twz_k<<<dim3(500, 32), blk, 0, stream>>>(Wout, Bh, Bl, 1024, 32000, 16000);
    mgemm_k<1><<<dim3(125, 32), blk, 0, stream>>>(Ahp, Alp, Bh, Bl, bout, out,
                                                  tokens, 1024, 32000, 16000);
}